// Round 3
// baseline (319.177 us; speedup 1.0000x reference)
//
#include <hip/hip_runtime.h>

#define B_SZ 4
#define SEQ  2048
#define CH   768
#define NH   12
#define HD   64

typedef float f32x4  __attribute__((ext_vector_type(4)));
typedef __bf16 bf16x8 __attribute__((ext_vector_type(8)));
typedef __bf16 bf16x2 __attribute__((ext_vector_type(2)));

#define MFMA16(a,b,c) __builtin_amdgcn_mfma_f32_16x16x32_bf16(a,b,c,0,0,0)

// scale = 1/sqrt(64) * log2(e)  -> softmax uses exp2
#define QSCALE 0.1803368801111204f

#if __has_builtin(__builtin_amdgcn_exp2f)
#define EXP2(x) __builtin_amdgcn_exp2f(x)
#else
#define EXP2(x) exp2f(x)
#endif

// flash LDS swizzle
#define SWZ(row) (((row) ^ ((row) >> 3)) & 7)

__device__ __forceinline__ unsigned pack2(float a, float b) {
    union { bf16x2 v; unsigned u; } p;
    p.v[0] = (__bf16)a; p.v[1] = (__bf16)b;
    return p.u;
}

// async global->LDS, 16B per lane. lds dest must be wave-uniform base + lane*16.
__device__ __forceinline__ void lds_dma16(const void* g, void* l) {
    __builtin_amdgcn_global_load_lds(
        (const __attribute__((address_space(1))) void*)g,
        (__attribute__((address_space(3))) void*)(unsigned)(unsigned long long)l,
        16, 0, 0);
}

// ---------------- fused fp32 -> bf16 convert (x | qkv_w | proj_w in one launch) ------------
#define NBLK_X  6144   // 6291456 / 1024
#define NBLK_W  1728   // 1769472 / 1024
#define NBLK_P   576   //  589824 / 1024
__global__ __launch_bounds__(256) void convert_all(const float* __restrict__ x,
                                                   const float* __restrict__ w,
                                                   const float* __restrict__ p,
                                                   __bf16* __restrict__ ox,
                                                   __bf16* __restrict__ ow,
                                                   __bf16* __restrict__ op) {
    int blk = blockIdx.x;
    const float* src;
    __bf16* dst;
    int base;
    if (blk < NBLK_X)               { src = x; dst = ox; base = blk; }
    else if (blk < NBLK_X + NBLK_W) { src = w; dst = ow; base = blk - NBLK_X; }
    else                            { src = p; dst = op; base = blk - NBLK_X - NBLK_W; }
    int i = (base * 256 + threadIdx.x) * 4;
    float4 v = *(const float4*)(src + i);
    union { __bf16 h[4]; uint2 u; } o;
    o.h[0] = (__bf16)v.x; o.h[1] = (__bf16)v.y; o.h[2] = (__bf16)v.z; o.h[3] = (__bf16)v.w;
    *(uint2*)(dst + i) = o.u;
}

// ---------------- 128x128 tile (BK=64) MFMA mainloop: C = A(MxK) * B(NxK)^T ----------------
// LDS layout: row-major [128][64] bf16, 16B chunk c stored at phys chunk c ^ (row&7).
__device__ __forceinline__ void gemm128_loop(const __bf16* __restrict__ A,
                                             const __bf16* __restrict__ Bm,
                                             int K, int rowBlk, int colBlk,
                                             __bf16* As, __bf16* Bs,
                                             f32x4 acc[4][4]) {
    const int tid  = threadIdx.x;
    const int lane = tid & 63, wid = tid >> 6;
    const int quad = lane >> 4, l16 = lane & 15;
    const int wm = wid >> 1, wn = wid & 1;

    f32x4 z = {0.f, 0.f, 0.f, 0.f};
#pragma unroll
    for (int mi = 0; mi < 4; ++mi)
#pragma unroll
        for (int ni = 0; ni < 4; ++ni) acc[mi][ni] = z;

    for (int k0 = 0; k0 < K; k0 += 64) {
        __syncthreads();
#pragma unroll
        for (int i = 0; i < 4; ++i) {
            int s = i * 256 + tid;
            int row = s >> 3, pc = s & 7;
            int lc = pc ^ (row & 7);
            lds_dma16(A  + (size_t)(rowBlk + row) * K + k0 + lc * 8, As + s * 8);
            lds_dma16(Bm + (size_t)(colBlk + row) * K + k0 + lc * 8, Bs + s * 8);
        }
        __syncthreads();

#pragma unroll
        for (int kc = 0; kc < 2; ++kc) {
            bf16x8 af[4], bfr[4];
#pragma unroll
            for (int mi = 0; mi < 4; ++mi) {
                int row = wm * 64 + mi * 16 + l16;
                int pc = (quad + 4 * kc) ^ (row & 7);
                af[mi] = *(const bf16x8*)(As + row * 64 + pc * 8);
            }
#pragma unroll
            for (int ni = 0; ni < 4; ++ni) {
                int row = wn * 64 + ni * 16 + l16;
                int pc = (quad + 4 * kc) ^ (row & 7);
                bfr[ni] = *(const bf16x8*)(Bs + row * 64 + pc * 8);
            }
#pragma unroll
            for (int mi = 0; mi < 4; ++mi)
#pragma unroll
                for (int ni = 0; ni < 4; ++ni)
                    acc[mi][ni] = MFMA16(af[mi], bfr[ni], acc[mi][ni]);
        }
    }
}

// ---------------- QKV GEMM: X(8192x768) @ Wqkv(2304x768)^T, scatter to Q/K/Vt ----------------
__global__ __launch_bounds__(256) void qkv_gemm(const __bf16* __restrict__ Xb,
                                                const __bf16* __restrict__ Wb,
                                                __bf16* __restrict__ Qb,
                                                __bf16* __restrict__ Kb,
                                                __bf16* __restrict__ Vt) {
    __shared__ __bf16 smem[128 * 128];   // 32 KB: mainloop uses first 16 KB; V-epilogue all
    f32x4 acc[4][4];
    const int rowBlk = blockIdx.x * 128, colBlk = blockIdx.y * 128;
    gemm128_loop(Xb, Wb, CH, rowBlk, colBlk, smem, smem + 128 * 64, acc);

    const int tid = threadIdx.x;
    const int lane = tid & 63, wid = tid >> 6;
    const int quad = lane >> 4, l16 = lane & 15, wm = wid >> 1, wn = wid & 1;
    const int b = rowBlk >> 11, n0 = rowBlk & (SEQ - 1);

    if (colBlk < 2 * CH) {
        const int isK = (colBlk >= CH);
#pragma unroll
        for (int mi = 0; mi < 4; ++mi)
#pragma unroll
            for (int ni = 0; ni < 4; ++ni)
#pragma unroll
                for (int r = 0; r < 4; ++r) {
                    int n = n0 + wm * 64 + mi * 16 + quad * 4 + r;
                    int cc = colBlk - (isK ? CH : 0) + wn * 64 + ni * 16 + l16;
                    int h = cc >> 6, d = cc & 63;
                    size_t idx = (size_t)((b * NH + h) * SEQ + n) * HD + d;
                    float v = acc[mi][ni][r];
                    if (isK) Kb[idx] = (__bf16)v;
                    else     Qb[idx] = (__bf16)(v * QSCALE);
                }
    } else {
        // V: transpose through LDS, write V^T coalesced
        const int vblk = colBlk - 2 * CH;
        __syncthreads();
#pragma unroll
        for (int mi = 0; mi < 4; ++mi)
#pragma unroll
            for (int ni = 0; ni < 4; ++ni)
#pragma unroll
                for (int r = 0; r < 4; ++r) {
                    int rl = wm * 64 + mi * 16 + quad * 4 + r;   // n-local
                    int cl = wn * 64 + ni * 16 + l16;            // d-local
                    smem[cl * 128 + (((rl >> 3) ^ (cl & 15)) << 3) + (rl & 7)] =
                        (__bf16)acc[mi][ni][r];
                }
        __syncthreads();
        const int dl = tid >> 1;
        const int d  = vblk + dl;
        const int h  = d >> 6, dd = d & 63;
        const size_t base = (size_t)((b * NH + h) * HD + dd) * SEQ + n0;
#pragma unroll
        for (int j2 = 0; j2 < 8; ++j2) {
            int j = (tid & 1) * 8 + j2;
            uint4 val = *(const uint4*)(smem + dl * 128 + ((j ^ (dl & 15)) << 3));
            *(uint4*)(Vt + base + j * 8) = val;
        }
    }
}

// ---------------- Flash attention v12: 2q-half x 2key-half wave split -------------------------
// Post-mortem R2: V-from-global quadrupled traffic through the 64B/cy L1 (all 4 waves load the
// same tile) -> LDS staging restored. LDS-read-BW fix instead: wave (qh,kh) handles 64 queries
// x 32 keys, reading only its K-half (4KB) + V-half (4KB) per 64-key sub-tile = 8KB/wave
// (was 16KB). Per-CU LDS reads halve; staging, swizzle, grid (768, 3 blk/CU), MFMA count, and
// the proven pack/shfl P-exchange are unchanged. O and l are key-partial -> one cross-wave f32
// reduction via LDS in the epilogue (amortized over 32 tiles).
__global__ __launch_bounds__(256, 3) void flash_attn(const __bf16* __restrict__ Qb,
                                                     const __bf16* __restrict__ Kb,
                                                     const __bf16* __restrict__ Vt,
                                                     __bf16* __restrict__ Ab) {
    __shared__ __bf16 smem[26112];   // 51 KB: loop = 32KB staging (Ks0|Vs0|Ks1|Vs1);
                                     // epilogue = Sc f32[128][64] (alias 0..16K) | Ob[128][72]
                                     // at 16384 | Lsc 128 f32 at 25600

    const int tid  = threadIdx.x;
    const int lane = tid & 63, wid = tid >> 6;
    const int quad = lane >> 4, l16 = lane & 15;
    const int qh = wid & 1;          // query half  (64 q)
    const int kh = wid >> 1;         // key half    (32 k)

    // XCD-aware decode: blk%8 = XCD; 6 bh x 16 qblk per XCD.
    const int lin  = blockIdx.x;              // 0..767
    const int xcd  = lin & 7, idx = lin >> 3; // idx 0..95
    const int bh   = xcd * 6 + (idx >> 4);    // 0..47
    const int qblk = idx & 15;                // 0..15 (128 queries each)
    const int b    = bh / NH, head = bh - b * NH;

    // Q^T B-frags: 4 groups of 16 queries; lane n=l16=q, k(d) = kcd*32 + quad*8 + j
    bf16x8 qf[4][2];
#pragma unroll
    for (int qg = 0; qg < 4; ++qg) {
        const int q = qblk * 128 + qh * 64 + qg * 16 + l16;
#pragma unroll
        for (int kcd = 0; kcd < 2; ++kcd)
            qf[qg][kcd] = *(const bf16x8*)(Qb + (size_t)(bh * SEQ + q) * HD + kcd * 32 + quad * 8);
    }

    // key permutation (even/odd groups) for zero-cndmask P exchange; this wave's key rows
    const int key_e = ((l16 >> 2) << 3) + (l16 & 3);
    const int key_o = ((((l16 >> 2) ^ 1)) << 3) + 4 + (l16 & 3);
    const int key0 = (kh << 5) + key_e;
    const int key1 = (kh << 5) + key_o;
    const int swz_k0 = SWZ(key0), swz_k1 = SWZ(key1);

    f32x4 ot[4][4];                  // [qgroup][dgroup] partial O^T over this wave's keys
    f32x4 z = {0.f, 0.f, 0.f, 0.f};
#pragma unroll
    for (int qg = 0; qg < 4; ++qg)
#pragma unroll
        for (int dg = 0; dg < 4; ++dg) ot[qg][dg] = z;
    float l[4] = {0.f, 0.f, 0.f, 0.f};

    const __bf16* Kbh = Kb + (size_t)bh * SEQ * HD;
    const __bf16* Vbh = Vt + (size_t)bh * HD * SEQ;

    const int s_row = tid >> 3, s_pc = tid & 7;
    const int s_lc0 = s_pc ^ SWZ(s_row);
    const int s_lc1 = s_pc ^ SWZ(s_row + 32);

// 64-key sub-tile body; wave covers its kh key-half (32 keys) for 64 queries
#define PROCESS(KsP, VsP)                                                                     \
    do {                                                                                      \
        f32x4 st[4][2];                                                                       \
        _Pragma("unroll")                                                                     \
        for (int qg = 0; qg < 4; ++qg) { st[qg][0] = z; st[qg][1] = z; }                      \
        _Pragma("unroll")                                                                     \
        for (int kcd = 0; kcd < 2; ++kcd) {                                                   \
            const int c8 = quad + (kcd << 2);                                                 \
            bf16x8 kf0 = *(const bf16x8*)((KsP) + key0 * 64 + ((c8 ^ swz_k0) << 3));          \
            bf16x8 kf1 = *(const bf16x8*)((KsP) + key1 * 64 + ((c8 ^ swz_k1) << 3));          \
            _Pragma("unroll")                                                                 \
            for (int qg = 0; qg < 4; ++qg) {                                                  \
                st[qg][0] = MFMA16(kf0, qf[qg][kcd], st[qg][0]);                              \
                st[qg][1] = MFMA16(kf1, qf[qg][kcd], st[qg][1]);                              \
            }                                                                                 \
        }                                                                                     \
        bf16x8 pf[4];                                                                         \
        _Pragma("unroll")                                                                     \
        for (int qg = 0; qg < 4; ++qg) {                                                      \
            float p0 = EXP2(st[qg][0][0]), p1 = EXP2(st[qg][0][1]);                           \
            float p2 = EXP2(st[qg][0][2]), p3 = EXP2(st[qg][0][3]);                           \
            float p4 = EXP2(st[qg][1][0]), p5 = EXP2(st[qg][1][1]);                           \
            float p6 = EXP2(st[qg][1][2]), p7 = EXP2(st[qg][1][3]);                           \
            l[qg] += (p0 + p1) + (p2 + p3) + (p4 + p5) + (p6 + p7);                           \
            unsigned w0 = pack2(p0, p1), w1 = pack2(p2, p3);                                  \
            unsigned x0 = pack2(p4, p5), x1 = pack2(p6, p7);                                  \
            unsigned w2 = (unsigned)__shfl_xor((int)x0, 16, 64);                              \
            unsigned w3 = (unsigned)__shfl_xor((int)x1, 16, 64);                              \
            union { bf16x8 v; unsigned u[4]; } f;                                             \
            f.u[0] = w0; f.u[1] = w1; f.u[2] = w2; f.u[3] = w3;                               \
            pf[qg] = f.v;                                                                     \
        }                                                                                     \
        _Pragma("unroll")                                                                     \
        for (int dg = 0; dg < 4; ++dg) {                                                      \
            const int vrow = (dg << 4) + l16;                                                 \
            bf16x8 vf = *(const bf16x8*)((VsP) + vrow * 64 +                                  \
                                         (((quad + (kh << 2)) ^ SWZ(vrow)) << 3));            \
            _Pragma("unroll")                                                                 \
            for (int qg = 0; qg < 4; ++qg)                                                    \
                ot[qg][dg] = MFMA16(vf, pf[qg], ot[qg][dg]);                                  \
        }                                                                                     \
    } while (0)

    for (int kb = 0; kb < SEQ / 128; ++kb) {
        const int kbase = kb * 128;
        __syncthreads();   // prior-iteration LDS readers done
        // sub-tile 0: keys kbase..kbase+63
        lds_dma16(Kbh + (size_t)(kbase + s_row) * HD + s_lc0 * 8,            smem + tid * 8);
        lds_dma16(Kbh + (size_t)(kbase + s_row + 32) * HD + s_lc1 * 8,       smem + 2048 + tid * 8);
        lds_dma16(Vbh + (size_t)s_row * SEQ + kbase + s_lc0 * 8,             smem + 4096 + tid * 8);
        lds_dma16(Vbh + (size_t)(s_row + 32) * SEQ + kbase + s_lc1 * 8,      smem + 6144 + tid * 8);
        // sub-tile 1: keys kbase+64..kbase+127
        lds_dma16(Kbh + (size_t)(kbase + 64 + s_row) * HD + s_lc0 * 8,       smem + 8192 + tid * 8);
        lds_dma16(Kbh + (size_t)(kbase + 96 + s_row) * HD + s_lc1 * 8,       smem + 10240 + tid * 8);
        lds_dma16(Vbh + (size_t)s_row * SEQ + kbase + 64 + s_lc0 * 8,        smem + 12288 + tid * 8);
        lds_dma16(Vbh + (size_t)(s_row + 32) * SEQ + kbase + 64 + s_lc1 * 8, smem + 14336 + tid * 8);
        __syncthreads();   // drains dma

        PROCESS(smem, smem + 4096);
        PROCESS(smem + 8192, smem + 12288);
    }
#undef PROCESS

    // quad-reduce l: each lane then holds the 32-key partial sum for query qg*16+l16
#pragma unroll
    for (int qg = 0; qg < 4; ++qg) {
        l[qg] += __shfl_xor(l[qg], 16, 64);
        l[qg] += __shfl_xor(l[qg], 32, 64);
    }

    // ---- cross-wave (key-half) reduction + normalize + coalesced store ----
    __syncthreads();                                  // loop readers done; staging area dead
    float* Sc  = (float*)smem;                        // [128][64] f32 partials (32 KB)
    float* Lsc = (float*)(smem + 25600);              // 128 f32 partial denominators
    __bf16 (*Ob)[72] = (__bf16(*)[72])(smem + 16384); // transpose buffer (18 KB)

    if (kh == 1) {
#pragma unroll
        for (int qg = 0; qg < 4; ++qg) {
            const int qrow = (qh << 6) + (qg << 4) + l16;
#pragma unroll
            for (int dg = 0; dg < 4; ++dg)
                *(f32x4*)(Sc + qrow * 64 + (dg << 4) + (quad << 2)) = ot[qg][dg];
            if (quad == 0) Lsc[qrow] = l[qg];
        }
    }
    __syncthreads();
    if (kh == 0) {
#pragma unroll
        for (int qg = 0; qg < 4; ++qg) {
            const int qrow = (qh << 6) + (qg << 4) + l16;
            const float r = 1.f / (l[qg] + Lsc[qrow]);
#pragma unroll
            for (int dg = 0; dg < 4; ++dg) {
                f32x4 o = ot[qg][dg] + *(const f32x4*)(Sc + qrow * 64 + (dg << 4) + (quad << 2));
#pragma unroll
                for (int rr = 0; rr < 4; ++rr)
                    Ob[qrow][(dg << 4) + (quad << 2) + rr] = (__bf16)(o[rr] * r);
            }
        }
    }
    __syncthreads();
    {
        const int row = tid >> 1, c0 = (tid & 1) * 32;
        __bf16* dst = Ab + (size_t)(b * SEQ + qblk * 128 + row) * CH + head * HD + c0;
#pragma unroll
        for (int j = 0; j < 4; ++j)
            *(uint4*)(dst + j * 8) = *(const uint4*)(&Ob[row][c0 + j * 8]);
    }
}

// ---------------- Projection GEMM: Attn(8192x768) @ proj_w(768x768)^T + bias ----------------
__global__ __launch_bounds__(256) void proj_gemm(const __bf16* __restrict__ Ab,
                                                 const __bf16* __restrict__ Pw,
                                                 const float* __restrict__ bias,
                                                 float* __restrict__ out) {
    __shared__ __bf16 As[128 * 64];
    __shared__ __bf16 Bs[128 * 64];
    f32x4 acc[4][4];
    const int rowBlk = blockIdx.x * 128, colBlk = blockIdx.y * 128;
    gemm128_loop(Ab, Pw, CH, rowBlk, colBlk, As, Bs, acc);

    const int lane = threadIdx.x & 63, wid = threadIdx.x >> 6;
    const int quad = lane >> 4, l16 = lane & 15, wm = wid >> 1, wn = wid & 1;
#pragma unroll
    for (int mi = 0; mi < 4; ++mi)
#pragma unroll
        for (int ni = 0; ni < 4; ++ni)
#pragma unroll
            for (int r = 0; r < 4; ++r) {
                int row = rowBlk + wm * 64 + mi * 16 + quad * 4 + r;
                int col = colBlk + wn * 64 + ni * 16 + l16;
                out[(size_t)row * CH + col] = acc[mi][ni][r] + bias[col];
            }
}

extern "C" void kernel_launch(void* const* d_in, const int* in_sizes, int n_in,
                              void* d_out, int out_size, void* d_ws, size_t ws_size,
                              hipStream_t stream) {
    const float* x      = (const float*)d_in[0];
    const float* qkv_w  = (const float*)d_in[1];
    const float* proj_w = (const float*)d_in[2];
    const float* proj_b = (const float*)d_in[3];
    float* out = (float*)d_out;

    char* ws = (char*)d_ws;
    const size_t nX = (size_t)B_SZ * SEQ * CH;
    const size_t nW = (size_t)3 * CH * CH;
    const size_t nP = (size_t)CH * CH;
    const size_t nQ = (size_t)B_SZ * NH * SEQ * HD;

    __bf16* Xb = (__bf16*)(ws);
    __bf16* Wb = (__bf16*)(ws + 2 * nX);
    __bf16* Pw = (__bf16*)(ws + 2 * (nX + nW));
    __bf16* Qb = (__bf16*)(ws + 2 * (nX + nW + nP));
    __bf16* Kb = (__bf16*)(ws + 2 * (nX + nW + nP + nQ));
    __bf16* Vt = (__bf16*)(ws + 2 * (nX + nW + nP + 2 * nQ));
    __bf16* Ab = (__bf16*)(ws + 2 * (nX + nW + nP + 3 * nQ));

    convert_all<<<NBLK_X + NBLK_W + NBLK_P, 256, 0, stream>>>(x, qkv_w, proj_w, Xb, Wb, Pw);

    qkv_gemm<<<dim3((B_SZ * SEQ) / 128, (3 * CH) / 128), 256, 0, stream>>>(Xb, Wb, Qb, Kb, Vt);

    flash_attn<<<768, 256, 0, stream>>>(Qb, Kb, Vt, Ab);

    proj_gemm<<<dim3((B_SZ * SEQ) / 128, CH / 128), 256, 0, stream>>>(Ab, Pw, proj_b, out);
}